// Round 1
// baseline (86.085 us; speedup 1.0000x reference)
//
#include <hip/hip_runtime.h>

// Problem constants (from reference)
#define NB 8
#define HH 13
#define WW 13
#define AA 5
#define CC 20
#define NTOT (NB * HH * WW * AA)   // 6760
#define L_COORD 3.0f
#define OBJ_SCALE 5.0f
#define NOOBJ_SCALE 1.0f
#define INV_B (1.0f / 8.0f)
#define FS 13.0f                   // fs0 == fs1 == 13

__device__ __constant__ float c_anc[AA][2] = {
    {1.3221f, 1.73145f}, {3.19275f, 4.00944f}, {5.05587f, 8.09892f},
    {9.47112f, 4.84053f}, {11.2364f, 10.0071f}};

// ws layout: [0]: int counter (compacted positive count)
//            floats starting at byte 64: gt_x1[NTOT], gt_y1[NTOT], gt_x2[NTOT], gt_y2[NTOT], gt_area[NTOT]
#define WS_GT_OFFSET 64

__device__ __forceinline__ float block_reduce_sum(float v, float* sbuf) {
    // 64-lane wave reduce
    for (int o = 32; o > 0; o >>= 1) v += __shfl_down(v, o);
    int lane = threadIdx.x & 63;
    int wid  = threadIdx.x >> 6;
    if (lane == 0) sbuf[wid] = v;
    __syncthreads();
    float s = 0.f;
    if (threadIdx.x == 0) {
        int nw = (blockDim.x + 63) >> 6;
        for (int i = 0; i < nw; i++) s += sbuf[i];
    }
    __syncthreads();
    return s;  // valid only on thread 0
}

__global__ void init_kernel(float* out, int out_size, int* counter) {
    for (int i = 0; i < out_size; i++) out[i] = 0.f;
    *counter = 0;
}

__global__ void __launch_bounds__(256) yolo_main_kernel(
    const float* __restrict__ pred_cls,
    const float* __restrict__ pred_conf,
    const float* __restrict__ pred_bboxes,
    const float* __restrict__ label_cls,
    const float* __restrict__ label_conf,
    const float* __restrict__ label_bboxes,
    float* __restrict__ out,
    int* __restrict__ counter,
    float* __restrict__ gt_buf) {
    __shared__ float sred[4];
    int n = blockIdx.x * blockDim.x + threadIdx.x;
    float local = 0.f;
    if (n < NTOT) {
        int a = n % AA;
        int w = (n / AA) % WW;
        int h = (n / (AA * WW)) % HH;
        float ancx = (float)w, ancy = (float)h;
        float ancw = c_anc[a][0], anch = c_anc[a][1];

        bool pos = label_conf[n] > 0.f;
        if (pos) {
            // decode gt box
            float t0 = label_bboxes[n * 4 + 0];
            float t1 = label_bboxes[n * 4 + 1];
            float t2 = label_bboxes[n * 4 + 2];
            float t3 = label_bboxes[n * 4 + 3];
            float gw = expf(t2) * ancw / FS;
            float gh = expf(t3) * anch / FS;
            float gx = (t0 + ancx) / FS - gw * 0.5f;
            float gy = (t1 + ancy) / FS - gh * 0.5f;
            // decode pred box
            float p0 = pred_bboxes[n * 4 + 0];
            float p1 = pred_bboxes[n * 4 + 1];
            float p2 = pred_bboxes[n * 4 + 2];
            float p3 = pred_bboxes[n * 4 + 3];
            float pw = expf(p2) * ancw / FS;
            float ph = expf(p3) * anch / FS;
            float px = (p0 + ancx) / FS - pw * 0.5f;
            float py = (p1 + ancy) / FS - ph * 0.5f;

            // diag elem_iou(gt, pred)
            float gx2 = gx + gw, gy2 = gy + gh;
            float px2 = px + pw, py2 = py + ph;
            float dx = fminf(gx2, px2) - fmaxf(gx, px); dx = fmaxf(dx, 0.f);
            float dy = fminf(gy2, py2) - fmaxf(gy, py); dy = fmaxf(dy, 0.f);
            float inter = dx * dy;
            float iou = inter / (gw * gh + pw * ph - inter);

            // pos conf loss
            float pc = pred_conf[n];
            float dconf = pc - iou;
            local += OBJ_SCALE * dconf * dconf;

            // classification NLL (log_softmax + argmax(label))
            const float* lc   = label_cls + (long)n * CC;
            const float* pcls = pred_cls + (long)n * CC;
            int lbl = 0;
            float bl = lc[0];
            for (int i = 1; i < CC; i++) {
                float v = lc[i];
                if (v > bl) { bl = v; lbl = i; }
            }
            float mx = pcls[0];
            for (int i = 1; i < CC; i++) mx = fmaxf(mx, pcls[i]);
            float s = 0.f;
            for (int i = 0; i < CC; i++) s += expf(pcls[i] - mx);
            local += mx + logf(s) - pcls[lbl];

            // coord losses
            float dxc = p0 - t0, dyc = p1 - t1;
            local += L_COORD * (dxc * dxc + dyc * dyc);
            float dwc = p2 - t2, dhc = p3 - t3;
            float adw = fabsf(dwc), adh = fabsf(dhc);
            float hw = adw < 1.f ? 0.5f * dwc * dwc : adw - 0.5f;
            float hh2 = adh < 1.f ? 0.5f * dhc * dhc : adh - 0.5f;
            local += L_COORD * (hw + hh2);

            // compact this positive gt box for the neg-conf pass
            int idx = atomicAdd(counter, 1);
            gt_buf[idx]            = gx;
            gt_buf[NTOT + idx]     = gy;
            gt_buf[2 * NTOT + idx] = gx2;
            gt_buf[3 * NTOT + idx] = gy2;
            gt_buf[4 * NTOT + idx] = gw * gh;
        }
    }
    float bs = block_reduce_sum(local, sred);
    if (threadIdx.x == 0 && bs != 0.f) atomicAdd(out, bs * INV_B);
}

__global__ void __launch_bounds__(256) yolo_neg_kernel(
    const float* __restrict__ pred_conf,
    const float* __restrict__ pred_bboxes,
    const float* __restrict__ label_conf,
    float* __restrict__ out,
    const int* __restrict__ counter,
    const float* __restrict__ gt_buf) {
    __shared__ float sx1[256], sy1[256], sx2[256], sy2[256], sar[256];
    __shared__ float sred[4];
    int n = blockIdx.x * blockDim.x + threadIdx.x;
    int M = *counter;

    bool active = false;
    float px1 = 0.f, py1 = 0.f, px2 = 0.f, py2 = 0.f, parea = 1.f, diffsq = 0.f;
    if (n < NTOT) {
        float lcf = label_conf[n];
        if (!(lcf > 0.f)) {
            active = true;
            int a = n % AA;
            int w = (n / AA) % WW;
            int h = (n / (AA * WW)) % HH;
            float ancx = (float)w, ancy = (float)h;
            float ancw = c_anc[a][0], anch = c_anc[a][1];
            float p0 = pred_bboxes[n * 4 + 0];
            float p1 = pred_bboxes[n * 4 + 1];
            float p2 = pred_bboxes[n * 4 + 2];
            float p3 = pred_bboxes[n * 4 + 3];
            float pw = expf(p2) * ancw / FS;
            float ph = expf(p3) * anch / FS;
            px1 = (p0 + ancx) / FS - pw * 0.5f;
            py1 = (p1 + ancy) / FS - ph * 0.5f;
            px2 = px1 + pw;
            py2 = py1 + ph;
            parea = pw * ph;
            float d = pred_conf[n] - lcf;
            diffsq = d * d;
        }
    }

    float best = 0.f;
    for (int t0 = 0; t0 < M; t0 += 256) {
        int i = t0 + (int)threadIdx.x;
        if (i < M) {
            sx1[threadIdx.x] = gt_buf[i];
            sy1[threadIdx.x] = gt_buf[NTOT + i];
            sx2[threadIdx.x] = gt_buf[2 * NTOT + i];
            sy2[threadIdx.x] = gt_buf[3 * NTOT + i];
            sar[threadIdx.x] = gt_buf[4 * NTOT + i];
        }
        __syncthreads();
        int lim = min(256, M - t0);
        if (active) {
            for (int i2 = 0; i2 < lim; i2++) {
                float dx = fminf(px2, sx2[i2]) - fmaxf(px1, sx1[i2]);
                dx = fmaxf(dx, 0.f);
                float dy = fminf(py2, sy2[i2]) - fmaxf(py1, sy1[i2]);
                dy = fmaxf(dy, 0.f);
                float inter = dx * dy;
                float iou = inter / (sar[i2] + parea - inter);
                best = fmaxf(best, iou);
            }
        }
        __syncthreads();
    }

    float contrib = (active && best < 0.6f) ? diffsq : 0.f;
    float bs = block_reduce_sum(contrib, sred);
    if (threadIdx.x == 0 && bs != 0.f) atomicAdd(out, bs * (NOOBJ_SCALE * INV_B));
}

extern "C" void kernel_launch(void* const* d_in, const int* in_sizes, int n_in,
                              void* d_out, int out_size, void* d_ws, size_t ws_size,
                              hipStream_t stream) {
    const float* pred_cls     = (const float*)d_in[0];
    const float* pred_conf    = (const float*)d_in[1];
    const float* pred_bboxes  = (const float*)d_in[2];
    const float* label_cls    = (const float*)d_in[3];
    const float* label_conf   = (const float*)d_in[4];
    const float* label_bboxes = (const float*)d_in[5];
    float* out = (float*)d_out;

    int* counter  = (int*)d_ws;
    float* gt_buf = (float*)((char*)d_ws + WS_GT_OFFSET);

    const int block = 256;
    const int grid  = (NTOT + block - 1) / block;  // 27

    init_kernel<<<1, 1, 0, stream>>>(out, out_size, counter);
    yolo_main_kernel<<<grid, block, 0, stream>>>(
        pred_cls, pred_conf, pred_bboxes, label_cls, label_conf, label_bboxes,
        out, counter, gt_buf);
    yolo_neg_kernel<<<grid, block, 0, stream>>>(
        pred_conf, pred_bboxes, label_conf, out, counter, gt_buf);
}